// Round 1
// 145.934 us; speedup vs baseline: 1.0009x; 1.0009x over previous
//
#include <hip/hip_runtime.h>

// Problem constants (fixed by setup_inputs): B=32, C=64, H=W=32, N=16 branches.
#define CH      64
#define BATCH   32
#define NBR     16
#define HW4     256           // float4 per channel plane (H*W = 1024 floats)

// ---------------------------------------------------------------------------
// Kernel A: per-(batch, channel) sum / sumsq.
// grid = 512: b = bid & 31, cg = bid >> 5 (16 groups of 4 channels).
// bid % 8 == b % 8  ->  all 16 blocks of batch b land on the same XCD
// (round-robin heuristic), warming that XCD's L2 with x[b,:] for bn_apply,
// which uses the same b-to-XCD mapping.
// Each wave reduces one full channel plane (1024 floats, 4x coalesced float4
// per lane) -> one deterministic partial slot, no atomics, no LDS reduce.
// ---------------------------------------------------------------------------
__global__ void __launch_bounds__(256) bn_partial(const float* __restrict__ x,
                                                  float* __restrict__ partials) {
    const int b    = blockIdx.x & 31;
    const int cg   = blockIdx.x >> 5;     // 0..15
    const int wave = threadIdx.x >> 6;    // 0..3
    const int lane = threadIdx.x & 63;
    const int c    = cg * 4 + wave;

    const float4* xp = (const float4*)x + (b * CH + c) * HW4;
    float s = 0.f, sq = 0.f;
#pragma unroll
    for (int i = 0; i < 4; ++i) {
        const float4 v = xp[i * 64 + lane];
        s  += v.x + v.y + v.z + v.w;
        sq += v.x * v.x + v.y * v.y + v.z * v.z + v.w * v.w;
    }
#pragma unroll
    for (int off = 32; off > 0; off >>= 1) {
        s  += __shfl_down(s, off);
        sq += __shfl_down(sq, off);
    }
    if (lane == 0) {
        partials[(b * CH + c) * 2 + 0] = s;
        partials[(b * CH + c) * 2 + 1] = sq;
    }
}

// ---------------------------------------------------------------------------
// Kernel B: fused finalize + apply, write-locality-first.
// grid = 1024: b = bid & 31 (same XCD as bn_partial's b), n = (bid>>5) & 15,
// half = bid >> 9. Each block writes ONE CONTIGUOUS 128 KB output stream:
// out[b, n, half*32 .. half*32+31, :]. x[b] is re-read per branch, but it is
// L2/L3-resident (8 MiB total, XCD-warmed by kernel A) -- writes are the only
// HBM traffic that matters (128 MiB vs 8 MiB), so we optimize store streams,
// not register reuse of x.
// Preamble: threads 0..31 fold the 32 per-batch partials for their channel and
// emit scale/shift into LDS (out = a*x + s), replacing the old finalize kernel.
// ---------------------------------------------------------------------------
__global__ void __launch_bounds__(256) bn_apply(const float* __restrict__ x,
                                                const float* __restrict__ partials,
                                                const float* __restrict__ gamma,
                                                const float* __restrict__ beta,
                                                float* __restrict__ out) {
    const int bid  = blockIdx.x;
    const int b    = bid & 31;
    const int n    = (bid >> 5) & 15;
    const int half = bid >> 9;            // 0..1
    const int t    = threadIdx.x;         // 0..255

    __shared__ float sa[32], ss[32];
    if (t < 32) {
        const int c = half * 32 + t;
        float S = 0.f, Q = 0.f;
#pragma unroll
        for (int bb = 0; bb < 32; ++bb) {
            S += partials[(bb * CH + c) * 2 + 0];
            Q += partials[(bb * CH + c) * 2 + 1];
        }
        const float mean = S * (1.0f / 32768.0f);
        const float var  = Q * (1.0f / 32768.0f) - mean * mean;
        const float inv  = rsqrtf(var + 1e-5f);
        const float a    = gamma[n * CH + c] * inv;
        sa[t] = a;
        ss[t] = beta[n * CH + c] - a * mean;
    }
    __syncthreads();

    // 32 channel planes: per iteration a 1 KB coalesced wave read of x and a
    // 1 KB coalesced wave write; consecutive iterations are CONTIGUOUS in out.
    const float4* xp = (const float4*)x   + (b * CH + half * 32) * HW4 + t;
    float4*       op = (float4*)out + ((b * NBR + n) * CH + half * 32) * HW4 + t;
#pragma unroll 4
    for (int cc = 0; cc < 32; ++cc) {
        const float a = sa[cc];
        const float s = ss[cc];
        const float4 v = xp[cc * HW4];
        float4 o;
        o.x = fmaf(a, v.x, s);
        o.y = fmaf(a, v.y, s);
        o.z = fmaf(a, v.z, s);
        o.w = fmaf(a, v.w, s);
        op[cc * HW4] = o;
    }
}

extern "C" void kernel_launch(void* const* d_in, const int* in_sizes, int n_in,
                              void* d_out, int out_size, void* d_ws, size_t ws_size,
                              hipStream_t stream) {
    const float* x     = (const float*)d_in[0];   // [32,64,32,32]
    const float* gamma = (const float*)d_in[1];   // [16,64]
    const float* beta  = (const float*)d_in[2];   // [16,64]
    float* out = (float*)d_out;                   // [32,1024,32,32]
    float* ws  = (float*)d_ws;

    float* partials = ws;   // 32*64*2 = 4096 floats, deterministic slots

    bn_partial<<<512, 256, 0, stream>>>(x, partials);
    bn_apply  <<<1024, 256, 0, stream>>>(x, partials, gamma, beta, out);
}